// Round 1
// baseline (135.860 us; speedup 1.0000x reference)
//
#include <hip/hip_runtime.h>
#include <math.h>

// Problem constants (from setup_inputs: N=64, C=256, H=56, W=56, K=8)
#define NB   64
#define CB   256
#define KB   8
#define HWSZ 3136          // 56*56
#define HW4  784           // HWSZ/4
#define PLANES (NB*CB)     // 16384
#define EPSV 1e-5f

// ---------------------------------------------------------------------------
// Kernel 1: per-(n,c) spatial mean and mean-of-squares.
// One 256-thread block per plane; float4 loads; wave shuffle + LDS reduce.
// ---------------------------------------------------------------------------
__global__ __launch_bounds__(256) void k_stats(const float* __restrict__ x,
                                               float* __restrict__ xm,
                                               float* __restrict__ x2m) {
    const int plane = blockIdx.x;
    const float4* xp = (const float4*)(x + (size_t)plane * HWSZ);

    float s = 0.f, s2 = 0.f;
    for (int i = threadIdx.x; i < HW4; i += 256) {
        float4 v = xp[i];
        s  += v.x + v.y + v.z + v.w;
        s2 += v.x*v.x + v.y*v.y + v.z*v.z + v.w*v.w;
    }
    // wave-64 butterfly reduce
    #pragma unroll
    for (int off = 32; off > 0; off >>= 1) {
        s  += __shfl_down(s,  off, 64);
        s2 += __shfl_down(s2, off, 64);
    }
    __shared__ float ls[4], ls2[4];
    const int lane = threadIdx.x & 63;
    const int w    = threadIdx.x >> 6;
    if (lane == 0) { ls[w] = s; ls2[w] = s2; }
    __syncthreads();
    if (threadIdx.x == 0) {
        float t  = ls[0]  + ls[1]  + ls[2]  + ls[3];
        float t2 = ls2[0] + ls2[1] + ls2[2] + ls2[3];
        xm[plane]  = t  * (1.f / HWSZ);
        x2m[plane] = t2 * (1.f / HWSZ);
    }
}

// ---------------------------------------------------------------------------
// Kernel 2 (single block, 1024 threads): logits -> softmax gates ->
// per-expert weighted stats (mu, rstd) -> per-(n,c) scale/shift.
// All operands are tiny (<=64 KB) and L2-hot.
// ---------------------------------------------------------------------------
__global__ __launch_bounds__(1024) void k_gates(const float* __restrict__ xm,
                                                const float* __restrict__ x2m,
                                                const float* __restrict__ Ww,   // [K,C]
                                                const float* __restrict__ Wb,   // [K]
                                                const float* __restrict__ alpha,// [C]
                                                const float* __restrict__ beta, // [C]
                                                float* __restrict__ scale,      // [N*C]
                                                float* __restrict__ shift) {    // [N*C]
    __shared__ float g[NB][KB];        // logits, then gates
    __shared__ float s_rstd[KB][CB];
    __shared__ float s_murstd[KB][CB];

    const int tid = threadIdx.x;

    // --- step 1: logits[n,k] = xm[n,:] . Ww[k,:] + Wb[k]  (512 pairs) ---
    if (tid < NB * KB) {
        const int n = tid >> 3, k = tid & 7;
        const float* xr = xm + n * CB;
        const float* wr = Ww + k * CB;
        float acc = 0.f;
        #pragma unroll 8
        for (int c = 0; c < CB; ++c) acc = fmaf(xr[c], wr[c], acc);
        g[n][k] = acc + Wb[k];
    }
    __syncthreads();

    // --- step 2: softmax over K per row n (threads 0..63) ---
    if (tid < NB) {
        float m = g[tid][0];
        #pragma unroll
        for (int k = 1; k < KB; ++k) m = fmaxf(m, g[tid][k]);
        float e[KB], s = 0.f;
        #pragma unroll
        for (int k = 0; k < KB; ++k) { e[k] = expf(g[tid][k] - m); s += e[k]; }
        const float inv = 1.f / s;
        #pragma unroll
        for (int k = 0; k < KB; ++k) g[tid][k] = e[k] * inv;
    }
    __syncthreads();

    // --- step 3: per-(k,c) weighted mean / rstd (2048 entries) ---
    for (int e = tid; e < KB * CB; e += 1024) {
        const int k = e >> 8;      // / CB
        const int c = e & 255;     // % CB
        float sg = 0.f, sm = 0.f, s2 = 0.f;
        #pragma unroll 8
        for (int n = 0; n < NB; ++n) {
            const float gn = g[n][k];      // LDS broadcast within wave
            sg += gn;
            sm = fmaf(gn, xm[n * CB + c], sm);
            s2 = fmaf(gn, x2m[n * CB + c], s2);
        }
        const float inv = 1.f / sg;
        const float mu  = sm * inv;
        const float var = fmaf(-mu, mu, s2 * inv);
        const float rs  = rsqrtf(var + EPSV);
        s_rstd[k][c]   = rs;
        s_murstd[k][c] = mu * rs;
    }
    __syncthreads();

    // --- step 4: per-(n,c) scale/shift (16384 entries) ---
    for (int e = tid; e < NB * CB; e += 1024) {
        const int n = e >> 8, c = e & 255;
        float a = 0.f, b = 0.f;
        #pragma unroll
        for (int k = 0; k < KB; ++k) {
            const float gk = g[n][k];
            a = fmaf(gk, s_rstd[k][c],   a);
            b = fmaf(gk, s_murstd[k][c], b);
        }
        const float al = alpha[c];
        scale[e] = al * a;
        shift[e] = beta[c] - al * b;
    }
}

// ---------------------------------------------------------------------------
// Kernel 3: out = x * scale[n,c] + shift[n,c], one block per plane, float4.
// ---------------------------------------------------------------------------
__global__ __launch_bounds__(256) void k_apply(const float* __restrict__ x,
                                               const float* __restrict__ scale,
                                               const float* __restrict__ shift,
                                               float* __restrict__ out) {
    const int plane = blockIdx.x;
    const float sc = scale[plane];   // uniform -> scalar load
    const float sh = shift[plane];
    const float4* xp = (const float4*)(x + (size_t)plane * HWSZ);
    float4* op = (float4*)(out + (size_t)plane * HWSZ);
    for (int i = threadIdx.x; i < HW4; i += 256) {
        float4 v = xp[i];
        float4 r;
        r.x = fmaf(v.x, sc, sh);
        r.y = fmaf(v.y, sc, sh);
        r.z = fmaf(v.z, sc, sh);
        r.w = fmaf(v.w, sc, sh);
        op[i] = r;
    }
}

extern "C" void kernel_launch(void* const* d_in, const int* in_sizes, int n_in,
                              void* d_out, int out_size, void* d_ws, size_t ws_size,
                              hipStream_t stream) {
    const float* x     = (const float*)d_in[0];
    const float* Ww    = (const float*)d_in[1];
    const float* Wb    = (const float*)d_in[2];
    const float* alpha = (const float*)d_in[3];
    const float* beta  = (const float*)d_in[4];
    float* out = (float*)d_out;

    float* ws    = (float*)d_ws;
    float* xm    = ws;                 // [N*C]
    float* x2m   = ws + PLANES;        // [N*C]
    float* scale = ws + 2 * PLANES;    // [N*C]
    float* shift = ws + 3 * PLANES;    // [N*C]

    k_stats<<<PLANES, 256, 0, stream>>>(x, xm, x2m);
    k_gates<<<1, 1024, 0, stream>>>(xm, x2m, Ww, Wb, alpha, beta, scale, shift);
    k_apply<<<PLANES, 256, 0, stream>>>(x, scale, shift, out);
}

// Round 3
// 105.895 us; speedup vs baseline: 1.2830x; 1.2830x over previous
//
#include <hip/hip_runtime.h>
#include <math.h>

// Problem constants (N=64, C=256, H=56, W=56, K=8)
#define NB   64
#define CB   256
#define KB   8
#define HWSZ 3136          // 56*56
#define HW4  784           // HWSZ/4
#define PLANES (NB*CB)     // 16384
#define EPSV 1e-5f

typedef float floatx4 __attribute__((ext_vector_type(4)));

// ---------------------------------------------------------------------------
// Kernel 1: per-(n,c) spatial mean and mean-of-squares.
// One 256-thread block per plane; float4 loads; wave shuffle + LDS reduce.
// Regular (caching) loads on purpose: x must be L3-resident for k_apply.
// ---------------------------------------------------------------------------
__global__ __launch_bounds__(256) void k_stats(const float* __restrict__ x,
                                               float* __restrict__ xm,
                                               float* __restrict__ x2m) {
    const int plane = blockIdx.x;
    const floatx4* xp = (const floatx4*)(x + (size_t)plane * HWSZ);

    float s = 0.f, s2 = 0.f;
    for (int i = threadIdx.x; i < HW4; i += 256) {
        floatx4 v = xp[i];
        s  += v.x + v.y + v.z + v.w;
        s2 += v.x*v.x + v.y*v.y + v.z*v.z + v.w*v.w;
    }
    #pragma unroll
    for (int off = 32; off > 0; off >>= 1) {
        s  += __shfl_down(s,  off, 64);
        s2 += __shfl_down(s2, off, 64);
    }
    __shared__ float ls[4], ls2[4];
    const int lane = threadIdx.x & 63;
    const int w    = threadIdx.x >> 6;
    if (lane == 0) { ls[w] = s; ls2[w] = s2; }
    __syncthreads();
    if (threadIdx.x == 0) {
        float t  = ls[0]  + ls[1]  + ls[2]  + ls[3];
        float t2 = ls2[0] + ls2[1] + ls2[2] + ls2[3];
        xm[plane]  = t  * (1.f / HWSZ);
        x2m[plane] = t2 * (1.f / HWSZ);
    }
}

// ---------------------------------------------------------------------------
// Kernel 2: one block per row n — logits[n,:] (8 dots of length 256) + softmax.
// ---------------------------------------------------------------------------
__global__ __launch_bounds__(256) void k_logits(const float* __restrict__ xm,
                                                const float* __restrict__ Ww,
                                                const float* __restrict__ Wb,
                                                float* __restrict__ g) {     // [N*K]
    const int n = blockIdx.x;
    const int k = threadIdx.x >> 5;
    const int l = threadIdx.x & 31;
    const float* xr = xm + n * CB;
    const float* wr = Ww + k * CB;
    float acc = 0.f;
    #pragma unroll
    for (int c = l; c < CB; c += 32) acc = fmaf(xr[c], wr[c], acc);
    #pragma unroll
    for (int off = 16; off > 0; off >>= 1) acc += __shfl_down(acc, off, 32);
    __shared__ float lg[KB];
    if (l == 0) lg[k] = acc + Wb[k];
    __syncthreads();
    if (threadIdx.x == 0) {
        float m = lg[0];
        #pragma unroll
        for (int j = 1; j < KB; ++j) m = fmaxf(m, lg[j]);
        float e[KB], s = 0.f;
        #pragma unroll
        for (int j = 0; j < KB; ++j) { e[j] = expf(lg[j] - m); s += e[j]; }
        const float inv = 1.f / s;
        #pragma unroll
        for (int j = 0; j < KB; ++j) g[n * KB + j] = e[j] * inv;
    }
}

// ---------------------------------------------------------------------------
// Kernel 3: one block per expert k, one thread per channel c:
// weighted mean/var over n -> rstd[k,c], mu*rstd[k,c].
// ---------------------------------------------------------------------------
__global__ __launch_bounds__(256) void k_expert(const float* __restrict__ xm,
                                                const float* __restrict__ x2m,
                                                const float* __restrict__ g,
                                                float* __restrict__ rstd,     // [K*C]
                                                float* __restrict__ murstd) { // [K*C]
    const int k = blockIdx.x;
    const int c = threadIdx.x;
    float sg = 0.f, sm = 0.f, s2 = 0.f;
    #pragma unroll 8
    for (int n = 0; n < NB; ++n) {
        const float gn = g[n * KB + k];        // uniform -> scalar load
        sg += gn;
        sm = fmaf(gn, xm[n * CB + c], sm);     // coalesced
        s2 = fmaf(gn, x2m[n * CB + c], s2);
    }
    const float inv = 1.f / sg;
    const float mu  = sm * inv;
    const float var = fmaf(-mu, mu, s2 * inv);
    const float rs  = rsqrtf(var + EPSV);
    rstd[k * CB + c]   = rs;
    murstd[k * CB + c] = mu * rs;
}

// ---------------------------------------------------------------------------
// Kernel 4: out = x * scale + shift. scale/shift computed in the prologue
// from block-uniform values (compiler scalarizes). Non-temporal stores keep
// x resident in the Infinity Cache so the x re-read is an L3 hit.
// ---------------------------------------------------------------------------
__global__ __launch_bounds__(256) void k_apply(const float* __restrict__ x,
                                               const float* __restrict__ g,
                                               const float* __restrict__ rstd,
                                               const float* __restrict__ murstd,
                                               const float* __restrict__ alpha,
                                               const float* __restrict__ beta,
                                               float* __restrict__ out) {
    const int plane = blockIdx.x;
    const int n = plane >> 8, c = plane & 255;

    float a = 0.f, b = 0.f;
    #pragma unroll
    for (int k = 0; k < KB; ++k) {
        const float gk = g[n * KB + k];        // all uniform -> s_loads
        a = fmaf(gk, rstd[k * CB + c],   a);
        b = fmaf(gk, murstd[k * CB + c], b);
    }
    const float al = alpha[c];
    const float sc = al * a;
    const float sh = fmaf(-al, b, beta[c]);

    const floatx4* xp = (const floatx4*)(x + (size_t)plane * HWSZ);
    floatx4* op = (floatx4*)(out + (size_t)plane * HWSZ);
    for (int i = threadIdx.x; i < HW4; i += 256) {
        floatx4 v = xp[i];
        floatx4 r;
        r.x = fmaf(v.x, sc, sh);
        r.y = fmaf(v.y, sc, sh);
        r.z = fmaf(v.z, sc, sh);
        r.w = fmaf(v.w, sc, sh);
        __builtin_nontemporal_store(r, &op[i]);
    }
}

extern "C" void kernel_launch(void* const* d_in, const int* in_sizes, int n_in,
                              void* d_out, int out_size, void* d_ws, size_t ws_size,
                              hipStream_t stream) {
    const float* x     = (const float*)d_in[0];
    const float* Ww    = (const float*)d_in[1];
    const float* Wb    = (const float*)d_in[2];
    const float* alpha = (const float*)d_in[3];
    const float* beta  = (const float*)d_in[4];
    float* out = (float*)d_out;

    float* ws     = (float*)d_ws;
    float* xm     = ws;                      // [N*C]
    float* x2m    = ws + PLANES;             // [N*C]
    float* g      = ws + 2 * PLANES;         // [N*K]
    float* rstd   = ws + 2 * PLANES + NB*KB; // [K*C]
    float* murstd = rstd + KB * CB;          // [K*C]

    k_stats <<<PLANES, 256, 0, stream>>>(x, xm, x2m);
    k_logits<<<NB,     256, 0, stream>>>(xm, Ww, Wb, g);
    k_expert<<<KB,     256, 0, stream>>>(xm, x2m, g, rstd, murstd);
    k_apply <<<PLANES, 256, 0, stream>>>(x, g, rstd, murstd, alpha, beta, out);
}